// Round 11
// baseline (495.502 us; speedup 1.0000x reference)
//
#include <hip/hip_runtime.h>

// ---- problem constants ----
#define B_  4
#define S_  2048
#define D_  1024
#define H_  16
#define DK_ 64
#define BH_ (B_*H_)
#define L2E 1.44269504088896f

typedef __attribute__((ext_vector_type(8))) short bf16x8;   // 8 bf16 = 4 VGPRs
typedef __attribute__((ext_vector_type(4))) float f32x4;
typedef __attribute__((ext_vector_type(16))) float f32x16;
typedef __attribute__((ext_vector_type(4))) unsigned u32x4;
typedef unsigned short u16;

__device__ __forceinline__ u16 f2bf(float f){
  unsigned u = __builtin_bit_cast(unsigned, f);
  u += 0x7fffu + ((u >> 16) & 1u);          // RNE (no NaNs in this problem)
  return (u16)(u >> 16);
}
__device__ __forceinline__ float bf2f(u16 h){
  unsigned u = ((unsigned)h) << 16;
  return __builtin_bit_cast(float, u);
}

// async global->LDS, 16B per lane; LDS dest is wave-uniform base + lane*16
#define GLD16(g,l) __builtin_amdgcn_global_load_lds( \
    (const __attribute__((address_space(1))) void*)(g), \
    (__attribute__((address_space(3))) void*)(l), 16, 0, 0)

#define MFMA16(a,b,c) __builtin_amdgcn_mfma_f32_16x16x32_bf16((a),(b),(c),0,0,0)
#define MFMA32(a,b,c) __builtin_amdgcn_mfma_f32_32x32x16_bf16((a),(b),(c),0,0,0)

// ---------------- merged preprocessing: cast x, cast 4 weights, trig table --
// blocks [0,2048): x fp32->bf16; [2048,3072): weights; [3072,3328): cos/sin
__global__ void prep_kernel(const float4* __restrict__ x,
                            const float4* __restrict__ w0, const float4* __restrict__ w1,
                            const float4* __restrict__ w2, const float4* __restrict__ w3,
                            ushort4* __restrict__ xb, ushort4* __restrict__ wb,
                            float* __restrict__ ct, float* __restrict__ st){
  const int bid = blockIdx.x;
  if (bid < 2048){
    const int n4 = B_*S_*D_/4;
    int i = bid*blockDim.x + threadIdx.x;
    for (; i < n4; i += 2048*256){
      float4 v = x[i];
      ushort4 o;
      o.x = f2bf(v.x); o.y = f2bf(v.y); o.z = f2bf(v.z); o.w = f2bf(v.w);
      xb[i] = o;
    }
  } else if (bid < 3072){
    const int per = D_*D_/4;
    int i = (bid-2048)*blockDim.x + threadIdx.x;
    for (; i < 4*per; i += 1024*256){
      int m = i / per, r = i - m*per;
      const float4* src = (m==0)?w0:(m==1)?w1:(m==2)?w2:w3;
      float4 v = src[r];
      ushort4 o;
      o.x = f2bf(v.x); o.y = f2bf(v.y); o.z = f2bf(v.z); o.w = f2bf(v.w);
      wb[i] = o;                                   // wq,wk,wv,wo contiguous in ws
    }
  } else {
    const int t = (bid-3072)*blockDim.x + threadIdx.x;  // [0, S_*32)
    const int i = t & 31, s = t >> 5;
    float expo = -(float)(2*i) * (1.0f/(float)DK_);
    float inv = powf(10000.0f, expo);
    float ang = (float)s * inv;
    ct[t] = cosf(ang);
    st[t] = sinf(ang);
  }
}

// ========== FUSED QKV NT GEMM: one block computes Q,K,V for one tile =======
// y_z[i,e] = sum_d x[i,d] * W_z[e,d], z=0,1,2 — A staged ONCE per k-step,
// 3 B-tiles staged alongside: 96 MFMA/wave per barrier window (3x the r1
// structure), L2 staging traffic 786->512 MB, windows/CU 96->32.
// Grid 512 = 64m x 8n (XCD-swizzled, 2 blocks/CU exact); 4 waves as 2x2;
// LDS 64 KB single-buffered: lA | lB0 | lB1 | lB2, each [128][64] u16.
// K-loop is the proven r1 2-barrier loop, verbatim structure.
// Epilogue: V direct transposed stores; Q then K through the 32 KB LDS
// repack tile with fused RoPE (Q pre-scaled 1/8).
__global__ __launch_bounds__(256, 2)
void gemm_qkv3(const u16* __restrict__ A,
               const u16* __restrict__ B0, const u16* __restrict__ B1, const u16* __restrict__ B2,
               u16* __restrict__ O0, u16* __restrict__ O1, u16* __restrict__ O2,
               const float* __restrict__ ct, const float* __restrict__ st){
  __shared__ __align__(16) u16 lds[32768];       // 64 KB

  // bijective XCD swizzle: 512 = 8 * 64
  const int id = (int)blockIdx.x;
  const int swz = (id & 7)*64 + (id >> 3);
  const int m0 = (swz >> 3) * 128, n0 = (swz & 7) * 128;

  const int tid = threadIdx.x, wave = tid>>6, lane = tid&63;
  const int wm = wave>>1, wn = wave&1;
  const int srow = lane>>3, scol = (lane&7)*8;
  const int l15 = lane & 15, l4 = lane >> 4;

  f32x4 acc[3][4][4];
  #pragma unroll
  for (int z=0;z<3;++z)
    #pragma unroll
    for (int m=0;m<4;++m)
      #pragma unroll
      for (int n=0;n<4;++n) acc[z][m][n] = (f32x4){0.f,0.f,0.f,0.f};

  #pragma unroll 1
  for (int k0 = 0; k0 < D_; k0 += 64){
    #pragma unroll
    for (int j=0;j<4;++j){
      const int rb = (wave*4 + j)*8;                  // 8 rows per instr (1KB)
      GLD16(A  + (size_t)(m0 + rb + srow)*D_ + k0 + scol, lds + rb*64);
      GLD16(B0 + (size_t)(n0 + rb + srow)*D_ + k0 + scol, lds +  8192 + rb*64);
      GLD16(B1 + (size_t)(n0 + rb + srow)*D_ + k0 + scol, lds + 16384 + rb*64);
      GLD16(B2 + (size_t)(n0 + rb + srow)*D_ + k0 + scol, lds + 24576 + rb*64);
    }
    __syncthreads();
    #pragma unroll
    for (int kk=0;kk<2;++kk){
      bf16x8 af[4];
      #pragma unroll
      for (int m=0;m<4;++m)
        af[m] = *(const bf16x8*)&lds[(wm*64 + m*16 + l15)*64 + kk*32 + l4*8];
      #pragma unroll
      for (int z=0;z<3;++z){
        const u16* lB = lds + 8192*(z+1);
        bf16x8 bfr[4];
        #pragma unroll
        for (int n=0;n<4;++n)
          bfr[n] = *(const bf16x8*)&lB[(wn*64 + n*16 + l15)*64 + kk*32 + l4*8];
        #pragma unroll
        for (int m=0;m<4;++m)
          #pragma unroll
          for (int n=0;n<4;++n)
            acc[z][m][n] = MFMA16(af[m], bfr[n], acc[z][m][n]);
      }
    }
    __syncthreads();
  }

  // ---- epilogue: C/D layout col = lane&15, row = (lane>>4)*4 + r  [m89] ----
  // V (z=2): direct transposed stores [bh][dk][s]; 4 consecutive s -> 8B store
  #pragma unroll
  for (int m=0;m<4;++m){
    const int rb = m0 + wm*64 + m*16 + (l4<<2);
    const int b = rb >> 11, s0 = rb & (S_-1);
    #pragma unroll
    for (int n=0;n<4;++n){
      const int e = n0 + wn*64 + n*16 + l15;
      const int h = e>>6, dk = e&63;
      ushort4 w4;
      w4.x = f2bf(acc[2][m][n][0]); w4.y = f2bf(acc[2][m][n][1]);
      w4.z = f2bf(acc[2][m][n][2]); w4.w = f2bf(acc[2][m][n][3]);
      *(ushort4*)(O2 + ((size_t)((b*H_ + h)*DK_ + dk))*S_ + s0) = w4;
    }
  }

  // Q (z=0) then K (z=1): LDS repack -> coalesced 16B stores with fused RoPE
  #pragma unroll 1
  for (int z=0; z<2; ++z){
    const float scale = (z == 0) ? 0.125f : 1.0f;   // Q pre-scaled 1/sqrt(DK)
    u16* Om = (z == 0) ? O0 : O1;
    #pragma unroll
    for (int m=0;m<4;++m){
      const int lr0 = wm*64 + m*16 + (l4<<2);
      #pragma unroll
      for (int n=0;n<4;++n){
        const int lc = wn*64 + n*16 + l15;
        #pragma unroll
        for (int r=0;r<4;++r){
          const int lr = lr0 + r;
          lds[lr*128 + (lc ^ (((lr>>2)&7)<<4))] = f2bf(acc[z][m][n][r]);
        }
      }
    }
    __syncthreads();
    // readback: 8 chunks of 8 bf16 (= 4 RoPE pairs) per thread
    #pragma unroll
    for (int k=0;k<8;++k){
      const int cid = k*256 + tid;                // [0,2048)
      const int rr = cid >> 4, cc = cid & 15;
      bf16x8 v = *(const bf16x8*)&lds[rr*128 + ((cc*8) ^ (((rr>>2)&7)<<4))];
      const int i = m0 + rr, bb = i >> 11, s = i & (S_-1);
      const int e0 = n0 + cc*8, h = e0 >> 6, dk0 = e0 & 63;
      const float4 c4 = *(const float4*)(ct + s*32 + (dk0>>1));
      const float4 s4 = *(const float4*)(st + s*32 + (dk0>>1));
      const float cc4[4] = {c4.x,c4.y,c4.z,c4.w};
      const float ss4[4] = {s4.x,s4.y,s4.z,s4.w};
      bf16x8 o;
      #pragma unroll
      for (int j=0;j<4;++j){
        const float x0 = bf2f((u16)v[2*j]);
        const float x1 = bf2f((u16)v[2*j+1]);
        o[2*j]   = (short)f2bf((x0*cc4[j] - x1*ss4[j])*scale);
        o[2*j+1] = (short)f2bf((x0*ss4[j] + x1*cc4[j])*scale);
      }
      *(bf16x8*)(Om + ((size_t)((bb*H_ + h)*S_ + s))*DK_ + dk0) = o;
    }
    __syncthreads();
  }
}

// ---------------- out-projection NT GEMM (r1/r5 structure, fp32 out) -------
__global__ __launch_bounds__(256, 2)
void gemm_out(const u16* __restrict__ A, const u16* __restrict__ Bw,
              float* __restrict__ Cf){
  __shared__ __align__(16) u16 lAB[2*128*64];
  u16* const lA = lAB;
  u16* const lB = lAB + 128*64;

  const int id = (int)blockIdx.x;                 // 512 = 8 * 64
  const int swz = (id & 7)*64 + (id >> 3);
  const int m0 = (swz >> 3) * 128, n0 = (swz & 7) * 128;

  const int tid = threadIdx.x, wave = tid>>6, lane = tid&63;
  const int wm = wave>>1, wn = wave&1;
  const int srow = lane>>3, scol = (lane&7)*8;

  f32x4 acc[4][4];
  #pragma unroll
  for (int m=0;m<4;++m)
    #pragma unroll
    for (int n=0;n<4;++n) acc[m][n] = (f32x4){0.f,0.f,0.f,0.f};

  #pragma unroll 1
  for (int k0 = 0; k0 < D_; k0 += 64){
    #pragma unroll
    for (int j=0;j<4;++j){
      int rb = (wave*4 + j)*8;
      GLD16(A  + (size_t)(m0 + rb + srow)*D_ + k0 + scol, lA + rb*64);
      GLD16(Bw + (size_t)(n0 + rb + srow)*D_ + k0 + scol, lB + rb*64);
    }
    __syncthreads();
    #pragma unroll
    for (int kk=0;kk<2;++kk){
      bf16x8 af[4], bfr[4];
      #pragma unroll
      for (int m=0;m<4;++m) af[m]  = *(const bf16x8*)&lA[(wm*64 + m*16 + (lane&15))*64 + kk*32 + (lane>>4)*8];
      #pragma unroll
      for (int n=0;n<4;++n) bfr[n] = *(const bf16x8*)&lB[(wn*64 + n*16 + (lane&15))*64 + kk*32 + (lane>>4)*8];
      #pragma unroll
      for (int m=0;m<4;++m)
        #pragma unroll
        for (int n=0;n<4;++n)
          acc[m][n] = MFMA16(af[m], bfr[n], acc[m][n]);
    }
    __syncthreads();
  }

  #pragma unroll
  for (int m=0;m<4;++m){
    const int rb = m0 + wm*64 + m*16 + ((lane>>4)<<2);
    #pragma unroll
    for (int n=0;n<4;++n){
      const int e = n0 + wn*64 + n*16 + (lane&15);
      #pragma unroll
      for (int r=0;r<4;++r)
        Cf[(size_t)(rb + r)*D_ + e] = acc[m][n][r];
    }
  }
}

// ---------------- causal flash attention (swapped-operand, in-reg softmax) --
// 4 waves x 32 q-rows = 128 q rows per block; KV tiles of 64; DK=64.
// S^T = mfma(K,Q): lane owns q = lane&31 -> softmax is in-lane + 1 shfl.
// P -> bf16 via cvt_pk + permlane32_swap feeds PV directly (no P in LDS).
// O^T = mfma(V^T, P): q stays lane&31 -> rescale/1/l lane-local.
// K tile [64kv][64dk] and V^T tile [64dk][64kv] DOUBLE-BUFFERED in LDS via
// global_load_lds with pre-swizzled SOURCE addresses (chunk c -> c^(row&7));
// next tile's loads issued BEFORE compute so the barrier drain overlaps MFMA.
// PER-CU WORK BALANCE: qt = qmap[y] — equalizes per-CU total work under
// round-robin block->CU assignment (r10: +6us measured).
__global__ __launch_bounds__(256, 4)
void attn_kernel(const u16* __restrict__ Q, const u16* __restrict__ K,
                 const u16* __restrict__ Vt, u16* __restrict__ O){
  __shared__ __align__(16) u16 lK[2][64*64];
  __shared__ __align__(16) u16 lV[2][64*64];

  const int bh = blockIdx.x;
  const int qmap[16] = {15,14,13,12, 10,11,9,8, 5,4,6,7, 0,1,2,3};
  const int qt = qmap[blockIdx.y];
  const int b = bh >> 4, h = bh & 15;
  const int tid = threadIdx.x, wave = tid>>6, lane = tid&63;
  const int hi = lane >> 5, l31 = lane & 31;
  const int qw = qt*128 + wave*32;
  const int qg = qw + l31;
  const u16* Qb = Q  + (size_t)bh*S_*DK_;
  const u16* Kb = K  + (size_t)bh*S_*DK_;
  const u16* Vb = Vt + (size_t)bh*DK_*S_;

  // Q fragments (B-operand): q = lane&31 row, d-slot ds: d = ds*16 + hi*8 + e
  bf16x8 qf[4];
  #pragma unroll
  for (int ds=0; ds<4; ++ds)
    qf[ds] = *(const bf16x8*)(Qb + (size_t)qg*DK_ + ds*16 + hi*8);

  f32x16 oacc[2];
  oacc[0] = (f32x16)0.f; oacc[1] = (f32x16)0.f;
  float m_run = -1e30f, l_run = 0.f;

  const int srow8 = lane >> 3;               // staging row within 8-row group
  const int csw = ((lane&7) ^ srow8) << 3;   // pre-swizzled source chunk (u16 units)

  const int kv_end = (qt+1)*128;

  // prologue: stage tile 0 into buffer 0
  #pragma unroll
  for (int it=0; it<2; ++it){
    const int rb = (it*4 + wave)*8;
    const int row = rb + srow8;
    GLD16(Kb + (size_t)row*DK_ + csw, lK[0] + rb*64);
    GLD16(Vb + (size_t)row*S_ + csw,  lV[0] + rb*64);
  }
  __syncthreads();

  int cur = 0;
  for (int kv0 = 0; kv0 < kv_end; kv0 += 64){
    // --- issue next tile's loads into the other buffer (overlaps compute) ---
    const int nxt = kv0 + 64;
    if (nxt < kv_end){
      #pragma unroll
      for (int it=0; it<2; ++it){
        const int rb = (it*4 + wave)*8;
        const int row = rb + srow8;
        GLD16(Kb + (size_t)(nxt+row)*DK_ + csw, lK[cur^1] + rb*64);
        GLD16(Vb + (size_t)row*S_ + nxt + csw,  lV[cur^1] + rb*64);
      }
    }

    if (kv0 < qw + 32){          // wave has rows at/after this tile's start
      // --- S^T[kv][q] = K·Q^T ---
      f32x16 sacc[2];
      sacc[0] = (f32x16)0.f; sacc[1] = (f32x16)0.f;
      __builtin_amdgcn_s_setprio(1);
      #pragma unroll
      for (int kb=0; kb<2; ++kb){
        const int krow = kb*32 + l31;
        #pragma unroll
        for (int ds=0; ds<4; ++ds){
          bf16x8 kf = *(const bf16x8*)&lK[cur][krow*64 + (((ds*2+hi) ^ (krow&7))<<3)];
          sacc[kb] = MFMA32(kf, qf[ds], sacc[kb]);
        }
      }
      __builtin_amdgcn_s_setprio(0);

      // --- causal mask (diag-overlapping tiles only) ---
      if (kv0 + 63 > qw){
        #pragma unroll
        for (int kb=0; kb<2; ++kb)
          #pragma unroll
          for (int r=0; r<16; ++r){
            const int kvg = kv0 + kb*32 + 4*hi + (r&3) + 8*(r>>2);
            if (kvg > qg) sacc[kb][r] = -1e30f;
          }
      }

      // --- online softmax: all 32 vals belong to row q = lane&31 ---
      float mx = sacc[0][0];
      #pragma unroll
      for (int r=1; r<16; ++r) mx = fmaxf(mx, sacc[0][r]);
      #pragma unroll
      for (int r=0; r<16; ++r) mx = fmaxf(mx, sacc[1][r]);
      mx = fmaxf(mx, __shfl_xor(mx, 32));
      // defer-max (T13): only rescale when some row grew past 2^8 headroom
      if (!__all((mx - m_run)*L2E <= 8.0f)){
        const float mn = fmaxf(m_run, mx);
        const float alpha = exp2f((m_run - mn)*L2E);
        m_run = mn;
        l_run *= alpha;
        oacc[0] *= alpha;
        oacc[1] *= alpha;
      }
      const float nc = m_run * L2E;
      float ps = 0.f;
      #pragma unroll
      for (int kb=0; kb<2; ++kb)
        #pragma unroll
        for (int r=0; r<16; ++r){
          float v = exp2f(__builtin_fmaf(sacc[kb][r], L2E, -nc));
          sacc[kb][r] = v;
          ps += v;
        }
      ps += __shfl_xor(ps, 32);
      l_run += ps;

      // --- P -> bf16 B-frags: cvt_pk pairs + permlane32_swap (T12) ---
      bf16x8 pa[4];
      #pragma unroll
      for (int kb=0; kb<2; ++kb){
        unsigned w[8];
        #pragma unroll
        for (int i=0; i<8; ++i){
          float a = sacc[kb][2*i], b2 = sacc[kb][2*i+1];
          asm("v_cvt_pk_bf16_f32 %0, %1, %2" : "=v"(w[i]) : "v"(a), "v"(b2));
        }
        auto s02 = __builtin_amdgcn_permlane32_swap(w[0], w[2], false, false);
        auto s13 = __builtin_amdgcn_permlane32_swap(w[1], w[3], false, false);
        auto s46 = __builtin_amdgcn_permlane32_swap(w[4], w[6], false, false);
        auto s57 = __builtin_amdgcn_permlane32_swap(w[5], w[7], false, false);
        u32x4 ua = {s02[0], s13[0], s02[1], s13[1]};
        u32x4 ub = {s46[0], s57[0], s46[1], s57[1]};
        pa[kb*2+0] = __builtin_bit_cast(bf16x8, ua);
        pa[kb*2+1] = __builtin_bit_cast(bf16x8, ub);
      }

      // --- O^T[dk][q] += V^T · P ---
      __builtin_amdgcn_s_setprio(1);
      #pragma unroll
      for (int dkb=0; dkb<2; ++dkb){
        const int vrow = dkb*32 + l31;
        #pragma unroll
        for (int ks=0; ks<4; ++ks){
          bf16x8 vf = *(const bf16x8*)&lV[cur][vrow*64 + (((ks*2+hi) ^ (vrow&7))<<3)];
          oacc[dkb] = MFMA32(vf, pa[ks], oacc[dkb]);
        }
      }
      __builtin_amdgcn_s_setprio(0);
    }
    __syncthreads();   // drains this wave's prefetch loads; all buffers ready
    cur ^= 1;
  }

  // --- epilogue: lane owns output row q=qg; dk = dkb*32 + 8*(r>>2) + 4*hi + (r&3)
  const float inv = 1.0f / l_run;
  #pragma unroll
  for (int dkb=0; dkb<2; ++dkb)
    #pragma unroll
    for (int rq=0; rq<4; ++rq){
      ushort4 w4;
      w4.x = f2bf(oacc[dkb][rq*4+0]*inv);
      w4.y = f2bf(oacc[dkb][rq*4+1]*inv);
      w4.z = f2bf(oacc[dkb][rq*4+2]*inv);
      w4.w = f2bf(oacc[dkb][rq*4+3]*inv);
      const int dk0 = dkb*32 + 8*rq + 4*hi;
      *(ushort4*)(O + (size_t)(b*S_+qg)*D_ + h*DK_ + dk0) = w4;
    }
}

// ---------------- launch ----------------
extern "C" void kernel_launch(void* const* d_in, const int* in_sizes, int n_in,
                              void* d_out, int out_size, void* d_ws, size_t ws_size,
                              hipStream_t stream){
  const float* x  = (const float*)d_in[0];
  const float* Wq = (const float*)d_in[1];
  const float* Wk = (const float*)d_in[2];
  const float* Wv = (const float*)d_in[3];
  const float* Wo = (const float*)d_in[4];
  float* out = (float*)d_out;
  char* ws = (char*)d_ws;

  size_t off = 0;
  u16* xb  = (u16*)(ws + off); off += (size_t)B_*S_*D_*2;
  u16* wqb = (u16*)(ws + off); off += (size_t)D_*D_*2;
  u16* wkb = (u16*)(ws + off); off += (size_t)D_*D_*2;
  u16* wvb = (u16*)(ws + off); off += (size_t)D_*D_*2;
  u16* wob = (u16*)(ws + off); off += (size_t)D_*D_*2;
  u16* Qb  = (u16*)(ws + off); off += (size_t)BH_*S_*DK_*2;
  u16* Kb  = (u16*)(ws + off); off += (size_t)BH_*S_*DK_*2;
  u16* Vtb = (u16*)(ws + off); off += (size_t)BH_*S_*DK_*2;   // [bh][dk][s]
  u16* Ob  = (u16*)(ws + off); off += (size_t)B_*S_*D_*2;
  float* ct = (float*)(ws + off); off += (size_t)S_*32*4;
  float* st = (float*)(ws + off); off += (size_t)S_*32*4;

  // merged preprocessing: x-cast + 4 weight casts + trig table in one launch
  prep_kernel<<<3328,256,0,stream>>>((const float4*)x,
                                     (const float4*)Wq, (const float4*)Wk,
                                     (const float4*)Wv, (const float4*)Wo,
                                     (ushort4*)xb, (ushort4*)wqb, ct, st);

  // FUSED QKV: 512 blocks = 64m x 8n, A staged once for 3 outputs;
  // Q/K epilogue applies RoPE in-place, Q pre-scaled by 1/sqrt(DK)=0.125
  gemm_qkv3<<<512,256,0,stream>>>(xb, wqb,wkb,wvb, Qb,Kb,Vtb, ct, st);

  // causal flash attention (r2 structure; per-CU balanced qt permutation)
  attn_kernel<<<dim3(BH_, S_/128),256,0,stream>>>(Qb, Kb, Vtb, Ob);

  // output projection (fp32 out), flat grid 512
  gemm_out<<<512,256,0,stream>>>(Ob, wob, out);
}

// Round 12
// 189.766 us; speedup vs baseline: 2.6111x; 2.6111x over previous
//
#include <hip/hip_runtime.h>

// ---- problem constants ----
#define B_  4
#define S_  2048
#define D_  1024
#define H_  16
#define DK_ 64
#define BH_ (B_*H_)
#define L2E 1.44269504088896f

typedef __attribute__((ext_vector_type(8))) short bf16x8;   // 8 bf16 = 4 VGPRs
typedef __attribute__((ext_vector_type(4))) float f32x4;
typedef __attribute__((ext_vector_type(16))) float f32x16;
typedef __attribute__((ext_vector_type(4))) unsigned u32x4;
typedef unsigned short u16;

__device__ __forceinline__ u16 f2bf(float f){
  unsigned u = __builtin_bit_cast(unsigned, f);
  u += 0x7fffu + ((u >> 16) & 1u);          // RNE (no NaNs in this problem)
  return (u16)(u >> 16);
}
__device__ __forceinline__ float bf2f(u16 h){
  unsigned u = ((unsigned)h) << 16;
  return __builtin_bit_cast(float, u);
}

// async global->LDS, 16B per lane; LDS dest is wave-uniform base + lane*16
#define GLD16(g,l) __builtin_amdgcn_global_load_lds( \
    (const __attribute__((address_space(1))) void*)(g), \
    (__attribute__((address_space(3))) void*)(l), 16, 0, 0)

#define MFMA16(a,b,c) __builtin_amdgcn_mfma_f32_16x16x32_bf16((a),(b),(c),0,0,0)
#define MFMA32(a,b,c) __builtin_amdgcn_mfma_f32_32x32x16_bf16((a),(b),(c),0,0,0)

// ---------------- merged preprocessing: cast x, cast 4 weights, trig table --
// blocks [0,2048): x fp32->bf16; [2048,3072): weights; [3072,3328): cos/sin
__global__ void prep_kernel(const float4* __restrict__ x,
                            const float4* __restrict__ w0, const float4* __restrict__ w1,
                            const float4* __restrict__ w2, const float4* __restrict__ w3,
                            ushort4* __restrict__ xb, ushort4* __restrict__ wb,
                            float* __restrict__ ct, float* __restrict__ st){
  const int bid = blockIdx.x;
  if (bid < 2048){
    const int n4 = B_*S_*D_/4;
    int i = bid*blockDim.x + threadIdx.x;
    for (; i < n4; i += 2048*256){
      float4 v = x[i];
      ushort4 o;
      o.x = f2bf(v.x); o.y = f2bf(v.y); o.z = f2bf(v.z); o.w = f2bf(v.w);
      xb[i] = o;
    }
  } else if (bid < 3072){
    const int per = D_*D_/4;
    int i = (bid-2048)*blockDim.x + threadIdx.x;
    for (; i < 4*per; i += 1024*256){
      int m = i / per, r = i - m*per;
      const float4* src = (m==0)?w0:(m==1)?w1:(m==2)?w2:w3;
      float4 v = src[r];
      ushort4 o;
      o.x = f2bf(v.x); o.y = f2bf(v.y); o.z = f2bf(v.z); o.w = f2bf(v.w);
      wb[i] = o;                                   // wq,wk,wv,wo contiguous in ws
    }
  } else {
    const int t = (bid-3072)*blockDim.x + threadIdx.x;  // [0, S_*32)
    const int i = t & 31, s = t >> 5;
    float expo = -(float)(2*i) * (1.0f/(float)DK_);
    float inv = powf(10000.0f, expo);
    float ang = (float)s * inv;
    ct[t] = cosf(ang);
    st[t] = sinf(ang);
  }
}

// ---------------- NT GEMM: y[i,e] = sum_d A[i,d] * W[e,d] ----------------
// Single-buffered 32 KB m97-structure at lb(256,2) — the measured-best config
// (r5/r10: QKV 81.8us; dbuf/8-phase/lb(256,4)/bigger tiles/QKV-fusion all
// measured worse). Flat 1D grid with bijective XCD swizzle.
// MODE 0: nwg=1536 (=3z x 64m x 8n); z=0,1 (Q,K) write bf16 [bh][s][dk]
//         through an LDS repack epilogue with FUSED RoPE (Q pre-scaled 1/8);
//         z=2 (V) writes TRANSPOSED bf16 [bh][dk][s] for the attn PV B-frags.
// MODE 1: nwg=512; fp32 row-major [i][e] (final projection into d_out).
template<int MODE>
__global__ __launch_bounds__(256, 2)
void gemm_bt(const u16* __restrict__ A,
             const u16* __restrict__ B0, const u16* __restrict__ B1, const u16* __restrict__ B2,
             u16* __restrict__ O0, u16* __restrict__ O1, u16* __restrict__ O2,
             float* __restrict__ Cf,
             const float* __restrict__ ct, const float* __restrict__ st, int K){
  // lA/lB for the K-loop; same 32 KB reused as the 128x128 u16 epilogue tile
  __shared__ __align__(16) u16 lAB[2*128*64];
  u16* const lA = lAB;
  u16* const lB = lAB + 128*64;

  // ---- XCD-aware bijective swizzle of the flat grid ----
  const int id = (int)blockIdx.x;
  const int nchunk = (MODE==0) ? 192 : 64;       // nwg/8
  const int swz = (id & 7)*nchunk + (id >> 3);
  int z = 0, rem = swz;
  if (MODE == 0){ z = swz >> 9; rem = swz & 511; }
  const int m0 = (rem >> 3) * 128, n0 = (rem & 7) * 128;

  const u16* Bm = B0;
  u16* Om = O0;
  if (MODE == 0){
    if (z == 1){ Bm = B1; Om = O1; }
    else if (z == 2){ Bm = B2; Om = O2; }
  }
  const int tid = threadIdx.x, wave = tid>>6, lane = tid&63;
  const int wm = wave>>1, wn = wave&1;
  const int srow = lane>>3, scol = (lane&7)*8;

  f32x4 acc[4][4];
  #pragma unroll
  for (int m=0;m<4;++m)
    #pragma unroll
    for (int n=0;n<4;++n) acc[m][n] = (f32x4){0.f,0.f,0.f,0.f};

  #pragma unroll 1
  for (int k0 = 0; k0 < K; k0 += 64){
    #pragma unroll
    for (int j=0;j<4;++j){
      int rb = (wave*4 + j)*8;                       // 8 rows per instr (1KB)
      GLD16(A  + (size_t)(m0 + rb + srow)*K + k0 + scol, lA + rb*64);
      GLD16(Bm + (size_t)(n0 + rb + srow)*K + k0 + scol, lB + rb*64);
    }
    __syncthreads();
    #pragma unroll
    for (int kk=0;kk<2;++kk){
      bf16x8 af[4], bfr[4];
      #pragma unroll
      for (int m=0;m<4;++m) af[m]  = *(const bf16x8*)&lA[(wm*64 + m*16 + (lane&15))*64 + kk*32 + (lane>>4)*8];
      #pragma unroll
      for (int n=0;n<4;++n) bfr[n] = *(const bf16x8*)&lB[(wn*64 + n*16 + (lane&15))*64 + kk*32 + (lane>>4)*8];
      #pragma unroll
      for (int m=0;m<4;++m)
        #pragma unroll
        for (int n=0;n<4;++n)
          acc[m][n] = MFMA16(af[m], bfr[n], acc[m][n]);
    }
    __syncthreads();
  }

  // epilogue: C/D layout col = lane&15, row = (lane>>4)*4 + r  [m89]
  if (MODE == 0 && z != 2){
    // ---- Q/K: LDS repack -> coalesced 16B stores with fused RoPE ----
    const float scale = (z == 0) ? 0.125f : 1.0f;  // Q pre-scaled 1/sqrt(DK)
    #pragma unroll
    for (int m=0;m<4;++m){
      const int lr0 = wm*64 + m*16 + ((lane>>4)<<2);
      #pragma unroll
      for (int n=0;n<4;++n){
        const int lc = wn*64 + n*16 + (lane&15);
        #pragma unroll
        for (int r=0;r<4;++r){
          const int lr = lr0 + r;
          lAB[lr*128 + (lc ^ (((lr>>2)&7)<<4))] = f2bf(acc[m][n][r]);
        }
      }
    }
    __syncthreads();
    // readback: 8 chunks of 8 bf16 (= 4 RoPE pairs) per thread
    #pragma unroll
    for (int k=0;k<8;++k){
      const int cid = k*256 + tid;                // [0,2048)
      const int rr = cid >> 4, cc = cid & 15;
      bf16x8 v = *(const bf16x8*)&lAB[rr*128 + ((cc*8) ^ (((rr>>2)&7)<<4))];
      const int i = m0 + rr, bb = i >> 11, s = i & (S_-1);
      const int e0 = n0 + cc*8, h = e0 >> 6, dk0 = e0 & 63;
      const float4 c4 = *(const float4*)(ct + s*32 + (dk0>>1));
      const float4 s4 = *(const float4*)(st + s*32 + (dk0>>1));
      const float cc4[4] = {c4.x,c4.y,c4.z,c4.w};
      const float ss4[4] = {s4.x,s4.y,s4.z,s4.w};
      bf16x8 o;
      #pragma unroll
      for (int j=0;j<4;++j){
        const float x0 = bf2f((u16)v[2*j]);
        const float x1 = bf2f((u16)v[2*j+1]);
        o[2*j]   = (short)f2bf((x0*cc4[j] - x1*ss4[j])*scale);
        o[2*j+1] = (short)f2bf((x0*ss4[j] + x1*cc4[j])*scale);
      }
      *(bf16x8*)(Om + ((size_t)((bb*H_ + h)*S_ + s))*DK_ + dk0) = o;
    }
  } else {
    #pragma unroll
    for (int m=0;m<4;++m){
      const int rb = m0 + wm*64 + m*16 + ((lane>>4)<<2);
      #pragma unroll
      for (int n=0;n<4;++n){
        const int e = n0 + wn*64 + n*16 + (lane&15);
        if (MODE == 0){
          // V transposed: [bh][dk][s]; 4 consecutive s -> one 8B store
          const int h = e>>6, dk = e&63;
          const int b = rb >> 11, s0 = rb & (S_-1);
          ushort4 w4;
          w4.x = f2bf(acc[m][n][0]); w4.y = f2bf(acc[m][n][1]);
          w4.z = f2bf(acc[m][n][2]); w4.w = f2bf(acc[m][n][3]);
          *(ushort4*)(Om + ((size_t)((b*H_ + h)*DK_ + dk))*S_ + s0) = w4;
        } else {
          #pragma unroll
          for (int r=0;r<4;++r)
            Cf[(size_t)(rb + r)*D_ + e] = acc[m][n][r];
        }
      }
    }
  }
}

// ---------------- causal flash attention (swapped-operand, SPLIT-KV) -------
// Inner loop = the proven r2/r10 structure VERBATIM; only the KV range is
// parameterized. Heavy q-tiles (qt>=8) are split into two blocks (half0 =
// mask-free first half of KV, half1 = diagonal half); each writes a flash
// partial (raw O^T bf16, m, l) merged by merge_kernel. Light q-tiles
// (qt<8) write final output directly (unchanged path). Grid (BH, 24),
// y-map sorted by descending work: max block = 8.5 tile-units (was 16).
__global__ __launch_bounds__(256, 4)
void attn_kernel(const u16* __restrict__ Q, const u16* __restrict__ K,
                 const u16* __restrict__ Vt, u16* __restrict__ O,
                 u16* __restrict__ Opart, float* __restrict__ Mlb){
  __shared__ __align__(16) u16 lK[2][64*64];
  __shared__ __align__(16) u16 lV[2][64*64];

  const int bh = blockIdx.x;
  // (qt, half) sorted by descending work; hf = -1 marks light (unsplit)
  const int qtv[24] = {15,15,7,14,14,13,13,6,12,12,5,11,11,4,10,10,3,9,9,2,8,8,1,0};
  const int hfv[24] = {0,1,-1,0,1,0,1,-1,0,1,-1,0,1,-1,0,1,-1,0,1,-1,0,1,-1,-1};
  const int qt = qtv[blockIdx.y];
  const int hf = hfv[blockIdx.y];
  const int b = bh >> 4, h = bh & 15;
  const int tid = threadIdx.x, wave = tid>>6, lane = tid&63;
  const int hi = lane >> 5, l31 = lane & 31;
  const int qw = qt*128 + wave*32;
  const int qg = qw + l31;
  const u16* Qb = Q  + (size_t)bh*S_*DK_;
  const u16* Kb = K  + (size_t)bh*S_*DK_;
  const u16* Vb = Vt + (size_t)bh*DK_*S_;

  const int kv_begin = (hf == 1) ? (qt+1)*64 : 0;
  const int kv_end   = (hf == 0) ? (qt+1)*64 : (qt+1)*128;

  // Q fragments (B-operand): q = lane&31 row, d-slot ds: d = ds*16 + hi*8 + e
  bf16x8 qf[4];
  #pragma unroll
  for (int ds=0; ds<4; ++ds)
    qf[ds] = *(const bf16x8*)(Qb + (size_t)qg*DK_ + ds*16 + hi*8);

  f32x16 oacc[2];
  oacc[0] = (f32x16)0.f; oacc[1] = (f32x16)0.f;
  float m_run = -1e30f, l_run = 0.f;

  const int srow8 = lane >> 3;               // staging row within 8-row group
  const int csw = ((lane&7) ^ srow8) << 3;   // pre-swizzled source chunk (u16 units)

  // prologue: stage first tile into buffer 0
  #pragma unroll
  for (int it=0; it<2; ++it){
    const int rb = (it*4 + wave)*8;
    const int row = rb + srow8;
    GLD16(Kb + (size_t)(kv_begin+row)*DK_ + csw, lK[0] + rb*64);
    GLD16(Vb + (size_t)row*S_ + kv_begin + csw,  lV[0] + rb*64);
  }
  __syncthreads();

  int cur = 0;
  for (int kv0 = kv_begin; kv0 < kv_end; kv0 += 64){
    // --- issue next tile's loads into the other buffer (overlaps compute) ---
    const int nxt = kv0 + 64;
    if (nxt < kv_end){
      #pragma unroll
      for (int it=0; it<2; ++it){
        const int rb = (it*4 + wave)*8;
        const int row = rb + srow8;
        GLD16(Kb + (size_t)(nxt+row)*DK_ + csw, lK[cur^1] + rb*64);
        GLD16(Vb + (size_t)row*S_ + nxt + csw,  lV[cur^1] + rb*64);
      }
    }

    if (kv0 < qw + 32){          // wave has rows at/after this tile's start
      // --- S^T[kv][q] = K·Q^T ---
      f32x16 sacc[2];
      sacc[0] = (f32x16)0.f; sacc[1] = (f32x16)0.f;
      __builtin_amdgcn_s_setprio(1);
      #pragma unroll
      for (int kb=0; kb<2; ++kb){
        const int krow = kb*32 + l31;
        #pragma unroll
        for (int ds=0; ds<4; ++ds){
          bf16x8 kf = *(const bf16x8*)&lK[cur][krow*64 + (((ds*2+hi) ^ (krow&7))<<3)];
          sacc[kb] = MFMA32(kf, qf[ds], sacc[kb]);
        }
      }
      __builtin_amdgcn_s_setprio(0);

      // --- causal mask (diag-overlapping tiles only) ---
      if (kv0 + 63 > qw){
        #pragma unroll
        for (int kb=0; kb<2; ++kb)
          #pragma unroll
          for (int r=0; r<16; ++r){
            const int kvg = kv0 + kb*32 + 4*hi + (r&3) + 8*(r>>2);
            if (kvg > qg) sacc[kb][r] = -1e30f;
          }
      }

      // --- online softmax: all 32 vals belong to row q = lane&31 ---
      float mx = sacc[0][0];
      #pragma unroll
      for (int r=1; r<16; ++r) mx = fmaxf(mx, sacc[0][r]);
      #pragma unroll
      for (int r=0; r<16; ++r) mx = fmaxf(mx, sacc[1][r]);
      mx = fmaxf(mx, __shfl_xor(mx, 32));
      // defer-max (T13): only rescale when some row grew past 2^8 headroom
      if (!__all((mx - m_run)*L2E <= 8.0f)){
        const float mn = fmaxf(m_run, mx);
        const float alpha = exp2f((m_run - mn)*L2E);
        m_run = mn;
        l_run *= alpha;
        oacc[0] *= alpha;
        oacc[1] *= alpha;
      }
      const float nc = m_run * L2E;
      float ps = 0.f;
      #pragma unroll
      for (int kb=0; kb<2; ++kb)
        #pragma unroll
        for (int r=0; r<16; ++r){
          float v = exp2f(__builtin_fmaf(sacc[kb][r], L2E, -nc));
          sacc[kb][r] = v;
          ps += v;
        }
      ps += __shfl_xor(ps, 32);
      l_run += ps;

      // --- P -> bf16 B-frags: cvt_pk pairs + permlane32_swap (T12) ---
      bf16x8 pa[4];
      #pragma unroll
      for (int kb=0; kb<2; ++kb){
        unsigned w[8];
        #pragma unroll
        for (int i=0; i<8; ++i){
          float a = sacc[kb][2*i], b2 = sacc[kb][2*i+1];
          asm("v_cvt_pk_bf16_f32 %0, %1, %2" : "=v"(w[i]) : "v"(a), "v"(b2));
        }
        auto s02 = __builtin_amdgcn_permlane32_swap(w[0], w[2], false, false);
        auto s13 = __builtin_amdgcn_permlane32_swap(w[1], w[3], false, false);
        auto s46 = __builtin_amdgcn_permlane32_swap(w[4], w[6], false, false);
        auto s57 = __builtin_amdgcn_permlane32_swap(w[5], w[7], false, false);
        u32x4 ua = {s02[0], s13[0], s02[1], s13[1]};
        u32x4 ub = {s46[0], s57[0], s46[1], s57[1]};
        pa[kb*2+0] = __builtin_bit_cast(bf16x8, ua);
        pa[kb*2+1] = __builtin_bit_cast(bf16x8, ub);
      }

      // --- O^T[dk][q] += V^T · P ---
      __builtin_amdgcn_s_setprio(1);
      #pragma unroll
      for (int dkb=0; dkb<2; ++dkb){
        const int vrow = dkb*32 + l31;
        #pragma unroll
        for (int ks=0; ks<4; ++ks){
          bf16x8 vf = *(const bf16x8*)&lV[cur][vrow*64 + (((ks*2+hi) ^ (vrow&7))<<3)];
          oacc[dkb] = MFMA32(vf, pa[ks], oacc[dkb]);
        }
      }
      __builtin_amdgcn_s_setprio(0);
    }
    __syncthreads();   // drains this wave's prefetch loads; all buffers ready
    cur ^= 1;
  }

  // --- epilogue: lane owns output row q=qg; dk = dkb*32 + 8*(r>>2) + 4*hi + (r&3)
  if (hf < 0){
    // light: normalize + write final bf16 output (unchanged r10 path)
    const float inv = 1.0f / l_run;
    #pragma unroll
    for (int dkb=0; dkb<2; ++dkb)
      #pragma unroll
      for (int rq=0; rq<4; ++rq){
        ushort4 w4;
        w4.x = f2bf(oacc[dkb][rq*4+0]*inv);
        w4.y = f2bf(oacc[dkb][rq*4+1]*inv);
        w4.z = f2bf(oacc[dkb][rq*4+2]*inv);
        w4.w = f2bf(oacc[dkb][rq*4+3]*inv);
        const int dk0 = dkb*32 + 8*rq + 4*hi;
        *(ushort4*)(O + (size_t)(b*S_+qg)*D_ + h*DK_ + dk0) = w4;
      }
  } else {
    // heavy half: write flash partial (raw O^T bf16 + m,l per q-row)
    const size_t pidx = (size_t)((bh*8 + (qt-8))*2 + hf);
    u16* Pp = Opart + pidx*8192;                 // [128 q][64 dk] bf16
    float* Mp = Mlb + pidx*256;                  // [128 q][m,l] f32
    const int ql = wave*32 + l31;
    #pragma unroll
    for (int dkb=0; dkb<2; ++dkb)
      #pragma unroll
      for (int rq=0; rq<4; ++rq){
        ushort4 w4;
        w4.x = f2bf(oacc[dkb][rq*4+0]);
        w4.y = f2bf(oacc[dkb][rq*4+1]);
        w4.z = f2bf(oacc[dkb][rq*4+2]);
        w4.w = f2bf(oacc[dkb][rq*4+3]);
        const int dk0 = dkb*32 + 8*rq + 4*hi;
        *(ushort4*)(Pp + ql*64 + dk0) = w4;
      }
    if (hi == 0){ Mp[ql*2] = m_run; Mp[ql*2+1] = l_run; }
  }
}

// ---------------- merge the two flash partials of each heavy q-tile --------
// grid 512 = 64 bh x 8 qh; combined: m*=max, a_i=2^((m_i-m*)L2E),
// O = (O0*a0 + O1*a1) / (l0*a0 + l1*a1), written bf16 to O.
__global__ void merge_kernel(const u16* __restrict__ Opart,
                             const float* __restrict__ Mlb,
                             u16* __restrict__ O){
  const int bx = blockIdx.x;
  const int bh = bx >> 3, qh = bx & 7;
  const int b = bh >> 4, h = bh & 15;
  const int qt = qh + 8;
  const size_t base = (size_t)((bh*8 + qh)*2);
  const u16* P0 = Opart + base*8192;
  const u16* P1 = P0 + 8192;
  const float* M0 = Mlb + base*256;
  const float* M1 = M0 + 256;
  #pragma unroll
  for (int k=0;k<4;++k){
    const int c = k*256 + threadIdx.x;          // [0,1024)
    const int q = c >> 3, ck = c & 7;
    const float m0 = M0[q*2], l0 = M0[q*2+1];
    const float m1 = M1[q*2], l1 = M1[q*2+1];
    const float ms = fmaxf(m0, m1);
    const float a0 = exp2f((m0 - ms)*L2E);
    const float a1 = exp2f((m1 - ms)*L2E);
    const float inv = 1.0f / (l0*a0 + l1*a1);
    bf16x8 v0 = *(const bf16x8*)&P0[q*64 + ck*8];
    bf16x8 v1 = *(const bf16x8*)&P1[q*64 + ck*8];
    bf16x8 o;
    #pragma unroll
    for (int j=0;j<8;++j)
      o[j] = (short)f2bf((bf2f((u16)v0[j])*a0 + bf2f((u16)v1[j])*a1)*inv);
    *(bf16x8*)(O + ((size_t)(b*S_ + qt*128 + q))*D_ + h*DK_ + ck*8) = o;
  }
}

// ---------------- launch ----------------
extern "C" void kernel_launch(void* const* d_in, const int* in_sizes, int n_in,
                              void* d_out, int out_size, void* d_ws, size_t ws_size,
                              hipStream_t stream){
  const float* x  = (const float*)d_in[0];
  const float* Wq = (const float*)d_in[1];
  const float* Wk = (const float*)d_in[2];
  const float* Wv = (const float*)d_in[3];
  const float* Wo = (const float*)d_in[4];
  float* out = (float*)d_out;
  char* ws = (char*)d_ws;

  size_t off = 0;
  u16* xb  = (u16*)(ws + off); off += (size_t)B_*S_*D_*2;
  u16* wqb = (u16*)(ws + off); off += (size_t)D_*D_*2;
  u16* wkb = (u16*)(ws + off); off += (size_t)D_*D_*2;
  u16* wvb = (u16*)(ws + off); off += (size_t)D_*D_*2;
  u16* wob = (u16*)(ws + off); off += (size_t)D_*D_*2;
  u16* Qb  = (u16*)(ws + off); off += (size_t)BH_*S_*DK_*2;
  u16* Kb  = (u16*)(ws + off); off += (size_t)BH_*S_*DK_*2;
  u16* Vtb = (u16*)(ws + off); off += (size_t)BH_*S_*DK_*2;   // [bh][dk][s]
  u16* Ob  = (u16*)(ws + off); off += (size_t)B_*S_*D_*2;
  float* ct = (float*)(ws + off); off += (size_t)S_*32*4;
  float* st = (float*)(ws + off); off += (size_t)S_*32*4;

  // flash-partial scratch ALIASED onto buffers dead after the QKV GEMM:
  // Opart (16.78 MB) = xb; Mlb (1 MB) = wqb
  u16* Opart = xb;
  float* Mlb = (float*)wqb;

  // merged preprocessing: x-cast + 4 weight casts + trig table in one launch
  prep_kernel<<<3328,256,0,stream>>>((const float4*)x,
                                     (const float4*)Wq, (const float4*)Wk,
                                     (const float4*)Wv, (const float4*)Wo,
                                     (ushort4*)xb, (ushort4*)wqb, ct, st);

  // QKV projections: flat grid 1536 = 3z x 64m x 8n, XCD-swizzled in-kernel;
  // z=0/1 epilogue applies RoPE in-place, Q pre-scaled by 1/sqrt(DK)=0.125
  gemm_bt<0><<<1536,256,0,stream>>>(xb, wqb,wkb,wvb, Qb,Kb,Vtb, nullptr, ct, st, D_);

  // causal flash attention — split-KV: heavy q-tiles (qt>=8) as 2 half-range
  // blocks writing partials; light q-tiles write final output directly
  attn_kernel<<<dim3(BH_, 24),256,0,stream>>>(Qb, Kb, Vtb, Ob, Opart, Mlb);

  // combine heavy partials into final attention output
  merge_kernel<<<512,256,0,stream>>>(Opart, Mlb, Ob);

  // output projection (fp32 out), flat grid 512
  gemm_bt<1><<<512,256,0,stream>>>(Ob, wob,wob,wob, nullptr,nullptr,nullptr, out, nullptr, nullptr, D_);
}

// Round 13
// 175.343 us; speedup vs baseline: 2.8259x; 1.0823x over previous
//
#include <hip/hip_runtime.h>

// ---- problem constants ----
#define B_  4
#define S_  2048
#define D_  1024
#define H_  16
#define DK_ 64
#define BH_ (B_*H_)
#define L2E 1.44269504088896f

typedef __attribute__((ext_vector_type(8))) short bf16x8;   // 8 bf16 = 4 VGPRs
typedef __attribute__((ext_vector_type(4))) float f32x4;
typedef __attribute__((ext_vector_type(16))) float f32x16;
typedef __attribute__((ext_vector_type(4))) unsigned u32x4;
typedef unsigned short u16;

__device__ __forceinline__ u16 f2bf(float f){
  unsigned u = __builtin_bit_cast(unsigned, f);
  u += 0x7fffu + ((u >> 16) & 1u);          // RNE (no NaNs in this problem)
  return (u16)(u >> 16);
}
__device__ __forceinline__ float bf2f(u16 h){
  unsigned u = ((unsigned)h) << 16;
  return __builtin_bit_cast(float, u);
}

// async global->LDS, 16B per lane; LDS dest is wave-uniform base + lane*16
#define GLD16(g,l) __builtin_amdgcn_global_load_lds( \
    (const __attribute__((address_space(1))) void*)(g), \
    (__attribute__((address_space(3))) void*)(l), 16, 0, 0)

#define MFMA16(a,b,c) __builtin_amdgcn_mfma_f32_16x16x32_bf16((a),(b),(c),0,0,0)
#define MFMA32(a,b,c) __builtin_amdgcn_mfma_f32_32x32x16_bf16((a),(b),(c),0,0,0)

// ---------------- merged preprocessing: cast x, cast 4 weights, trig table --
// blocks [0,2048): x fp32->bf16; [2048,3072): weights; [3072,3328): cos/sin
__global__ void prep_kernel(const float4* __restrict__ x,
                            const float4* __restrict__ w0, const float4* __restrict__ w1,
                            const float4* __restrict__ w2, const float4* __restrict__ w3,
                            ushort4* __restrict__ xb, ushort4* __restrict__ wb,
                            float* __restrict__ ct, float* __restrict__ st){
  const int bid = blockIdx.x;
  if (bid < 2048){
    const int n4 = B_*S_*D_/4;
    int i = bid*blockDim.x + threadIdx.x;
    for (; i < n4; i += 2048*256){
      float4 v = x[i];
      ushort4 o;
      o.x = f2bf(v.x); o.y = f2bf(v.y); o.z = f2bf(v.z); o.w = f2bf(v.w);
      xb[i] = o;
    }
  } else if (bid < 3072){
    const int per = D_*D_/4;
    int i = (bid-2048)*blockDim.x + threadIdx.x;
    for (; i < 4*per; i += 1024*256){
      int m = i / per, r = i - m*per;
      const float4* src = (m==0)?w0:(m==1)?w1:(m==2)?w2:w3;
      float4 v = src[r];
      ushort4 o;
      o.x = f2bf(v.x); o.y = f2bf(v.y); o.z = f2bf(v.z); o.w = f2bf(v.w);
      wb[i] = o;                                   // wq,wk,wv,wo contiguous in ws
    }
  } else {
    const int t = (bid-3072)*blockDim.x + threadIdx.x;  // [0, S_*32)
    const int i = t & 31, s = t >> 5;
    float expo = -(float)(2*i) * (1.0f/(float)DK_);
    float inv = powf(10000.0f, expo);
    float ang = (float)s * inv;
    ct[t] = cosf(ang);
    st[t] = sinf(ang);
  }
}

// ---------------- NT GEMM: y[i,e] = sum_d A[i,d] * W[e,d] ----------------
// Single-buffered 32 KB m97-structure at lb(256,2) — the measured-best config
// (r5/r10: QKV 81.8us; dbuf/8-phase/lb(256,4)/bigger tiles/QKV-fusion and
// split variants all measured worse). Flat 1D grid, bijective XCD swizzle.
// MODE 0: nwg=1536 (=3z x 64m x 8n); z=0,1 (Q,K) write bf16 [bh][s][dk]
//         through an LDS repack epilogue with FUSED RoPE (Q pre-scaled 1/8);
//         z=2 (V) writes TRANSPOSED bf16 [bh][dk][s] for the attn PV B-frags.
// MODE 1: nwg=512; fp32 row-major [i][e] (final projection into d_out).
template<int MODE>
__global__ __launch_bounds__(256, 2)
void gemm_bt(const u16* __restrict__ A,
             const u16* __restrict__ B0, const u16* __restrict__ B1, const u16* __restrict__ B2,
             u16* __restrict__ O0, u16* __restrict__ O1, u16* __restrict__ O2,
             float* __restrict__ Cf,
             const float* __restrict__ ct, const float* __restrict__ st, int K){
  // lA/lB for the K-loop; same 32 KB reused as the 128x128 u16 epilogue tile
  __shared__ __align__(16) u16 lAB[2*128*64];
  u16* const lA = lAB;
  u16* const lB = lAB + 128*64;

  // ---- XCD-aware bijective swizzle of the flat grid ----
  const int id = (int)blockIdx.x;
  const int nchunk = (MODE==0) ? 192 : 64;       // nwg/8
  const int swz = (id & 7)*nchunk + (id >> 3);
  int z = 0, rem = swz;
  if (MODE == 0){ z = swz >> 9; rem = swz & 511; }
  const int m0 = (rem >> 3) * 128, n0 = (rem & 7) * 128;

  const u16* Bm = B0;
  u16* Om = O0;
  if (MODE == 0){
    if (z == 1){ Bm = B1; Om = O1; }
    else if (z == 2){ Bm = B2; Om = O2; }
  }
  const int tid = threadIdx.x, wave = tid>>6, lane = tid&63;
  const int wm = wave>>1, wn = wave&1;
  const int srow = lane>>3, scol = (lane&7)*8;

  f32x4 acc[4][4];
  #pragma unroll
  for (int m=0;m<4;++m)
    #pragma unroll
    for (int n=0;n<4;++n) acc[m][n] = (f32x4){0.f,0.f,0.f,0.f};

  #pragma unroll 1
  for (int k0 = 0; k0 < K; k0 += 64){
    #pragma unroll
    for (int j=0;j<4;++j){
      int rb = (wave*4 + j)*8;                       // 8 rows per instr (1KB)
      GLD16(A  + (size_t)(m0 + rb + srow)*K + k0 + scol, lA + rb*64);
      GLD16(Bm + (size_t)(n0 + rb + srow)*K + k0 + scol, lB + rb*64);
    }
    __syncthreads();
    #pragma unroll
    for (int kk=0;kk<2;++kk){
      bf16x8 af[4], bfr[4];
      #pragma unroll
      for (int m=0;m<4;++m) af[m]  = *(const bf16x8*)&lA[(wm*64 + m*16 + (lane&15))*64 + kk*32 + (lane>>4)*8];
      #pragma unroll
      for (int n=0;n<4;++n) bfr[n] = *(const bf16x8*)&lB[(wn*64 + n*16 + (lane&15))*64 + kk*32 + (lane>>4)*8];
      #pragma unroll
      for (int m=0;m<4;++m)
        #pragma unroll
        for (int n=0;n<4;++n)
          acc[m][n] = MFMA16(af[m], bfr[n], acc[m][n]);
    }
    __syncthreads();
  }

  // epilogue: C/D layout col = lane&15, row = (lane>>4)*4 + r  [m89]
  if (MODE == 0 && z != 2){
    // ---- Q/K: LDS repack -> coalesced 16B stores with fused RoPE ----
    const float scale = (z == 0) ? 0.125f : 1.0f;  // Q pre-scaled 1/sqrt(DK)
    #pragma unroll
    for (int m=0;m<4;++m){
      const int lr0 = wm*64 + m*16 + ((lane>>4)<<2);
      #pragma unroll
      for (int n=0;n<4;++n){
        const int lc = wn*64 + n*16 + (lane&15);
        #pragma unroll
        for (int r=0;r<4;++r){
          const int lr = lr0 + r;
          lAB[lr*128 + (lc ^ (((lr>>2)&7)<<4))] = f2bf(acc[m][n][r]);
        }
      }
    }
    __syncthreads();
    // readback: 8 chunks of 8 bf16 (= 4 RoPE pairs) per thread
    #pragma unroll
    for (int k=0;k<8;++k){
      const int cid = k*256 + tid;                // [0,2048)
      const int rr = cid >> 4, cc = cid & 15;
      bf16x8 v = *(const bf16x8*)&lAB[rr*128 + ((cc*8) ^ (((rr>>2)&7)<<4))];
      const int i = m0 + rr, bb = i >> 11, s = i & (S_-1);
      const int e0 = n0 + cc*8, h = e0 >> 6, dk0 = e0 & 63;
      const float4 c4 = *(const float4*)(ct + s*32 + (dk0>>1));
      const float4 s4 = *(const float4*)(st + s*32 + (dk0>>1));
      const float cc4[4] = {c4.x,c4.y,c4.z,c4.w};
      const float ss4[4] = {s4.x,s4.y,s4.z,s4.w};
      bf16x8 o;
      #pragma unroll
      for (int j=0;j<4;++j){
        const float x0 = bf2f((u16)v[2*j]);
        const float x1 = bf2f((u16)v[2*j+1]);
        o[2*j]   = (short)f2bf((x0*cc4[j] - x1*ss4[j])*scale);
        o[2*j+1] = (short)f2bf((x0*ss4[j] + x1*cc4[j])*scale);
      }
      *(bf16x8*)(Om + ((size_t)((bb*H_ + h)*S_ + s))*DK_ + dk0) = o;
    }
  } else {
    #pragma unroll
    for (int m=0;m<4;++m){
      const int rb = m0 + wm*64 + m*16 + ((lane>>4)<<2);
      #pragma unroll
      for (int n=0;n<4;++n){
        const int e = n0 + wn*64 + n*16 + (lane&15);
        if (MODE == 0){
          // V transposed: [bh][dk][s]; 4 consecutive s -> one 8B store
          const int h = e>>6, dk = e&63;
          const int b = rb >> 11, s0 = rb & (S_-1);
          ushort4 w4;
          w4.x = f2bf(acc[m][n][0]); w4.y = f2bf(acc[m][n][1]);
          w4.z = f2bf(acc[m][n][2]); w4.w = f2bf(acc[m][n][3]);
          *(ushort4*)(Om + ((size_t)((b*H_ + h)*DK_ + dk))*S_ + s0) = w4;
        } else {
          #pragma unroll
          for (int r=0;r<4;++r)
            Cf[(size_t)(rb + r)*D_ + e] = acc[m][n][r];
        }
      }
    }
  }
}

// ---------------- causal flash attention (swapped-operand, in-reg softmax) --
// 4 waves x 32 q-rows = 128 q rows per block; KV tiles of 64; DK=64.
// S^T = mfma(K,Q): lane owns q = lane&31 -> softmax is in-lane + 1 shfl.
// P -> bf16 via cvt_pk + permlane32_swap feeds PV directly (no P in LDS).
// O^T = mfma(V^T, P): q stays lane&31 -> rescale/1/l lane-local.
// K tile [64kv][64dk] and V^T tile [64dk][64kv] DOUBLE-BUFFERED in LDS via
// global_load_lds with pre-swizzled SOURCE addresses (chunk c -> c^(row&7));
// next tile's loads issued BEFORE compute so the barrier drain overlaps MFMA.
// PER-CU WORK BALANCE: qt = qmap[y] — equalizes per-CU total work under
// round-robin block->CU assignment (r10: +6us measured; split-KV and
// q-tile pairing both measured worse).
__global__ __launch_bounds__(256, 4)
void attn_kernel(const u16* __restrict__ Q, const u16* __restrict__ K,
                 const u16* __restrict__ Vt, u16* __restrict__ O){
  __shared__ __align__(16) u16 lK[2][64*64];
  __shared__ __align__(16) u16 lV[2][64*64];

  const int bh = blockIdx.x;
  const int qmap[16] = {15,14,13,12, 10,11,9,8, 5,4,6,7, 0,1,2,3};
  const int qt = qmap[blockIdx.y];
  const int b = bh >> 4, h = bh & 15;
  const int tid = threadIdx.x, wave = tid>>6, lane = tid&63;
  const int hi = lane >> 5, l31 = lane & 31;
  const int qw = qt*128 + wave*32;
  const int qg = qw + l31;
  const u16* Qb = Q  + (size_t)bh*S_*DK_;
  const u16* Kb = K  + (size_t)bh*S_*DK_;
  const u16* Vb = Vt + (size_t)bh*DK_*S_;

  // Q fragments (B-operand): q = lane&31 row, d-slot ds: d = ds*16 + hi*8 + e
  bf16x8 qf[4];
  #pragma unroll
  for (int ds=0; ds<4; ++ds)
    qf[ds] = *(const bf16x8*)(Qb + (size_t)qg*DK_ + ds*16 + hi*8);

  f32x16 oacc[2];
  oacc[0] = (f32x16)0.f; oacc[1] = (f32x16)0.f;
  float m_run = -1e30f, l_run = 0.f;

  const int srow8 = lane >> 3;               // staging row within 8-row group
  const int csw = ((lane&7) ^ srow8) << 3;   // pre-swizzled source chunk (u16 units)

  const int kv_end = (qt+1)*128;

  // prologue: stage tile 0 into buffer 0
  #pragma unroll
  for (int it=0; it<2; ++it){
    const int rb = (it*4 + wave)*8;
    const int row = rb + srow8;
    GLD16(Kb + (size_t)row*DK_ + csw, lK[0] + rb*64);
    GLD16(Vb + (size_t)row*S_ + csw,  lV[0] + rb*64);
  }
  __syncthreads();

  int cur = 0;
  for (int kv0 = 0; kv0 < kv_end; kv0 += 64){
    // --- issue next tile's loads into the other buffer (overlaps compute) ---
    const int nxt = kv0 + 64;
    if (nxt < kv_end){
      #pragma unroll
      for (int it=0; it<2; ++it){
        const int rb = (it*4 + wave)*8;
        const int row = rb + srow8;
        GLD16(Kb + (size_t)(nxt+row)*DK_ + csw, lK[cur^1] + rb*64);
        GLD16(Vb + (size_t)row*S_ + nxt + csw,  lV[cur^1] + rb*64);
      }
    }

    if (kv0 < qw + 32){          // wave has rows at/after this tile's start
      // --- S^T[kv][q] = K·Q^T ---
      f32x16 sacc[2];
      sacc[0] = (f32x16)0.f; sacc[1] = (f32x16)0.f;
      __builtin_amdgcn_s_setprio(1);
      #pragma unroll
      for (int kb=0; kb<2; ++kb){
        const int krow = kb*32 + l31;
        #pragma unroll
        for (int ds=0; ds<4; ++ds){
          bf16x8 kf = *(const bf16x8*)&lK[cur][krow*64 + (((ds*2+hi) ^ (krow&7))<<3)];
          sacc[kb] = MFMA32(kf, qf[ds], sacc[kb]);
        }
      }
      __builtin_amdgcn_s_setprio(0);

      // --- causal mask (diag-overlapping tiles only) ---
      if (kv0 + 63 > qw){
        #pragma unroll
        for (int kb=0; kb<2; ++kb)
          #pragma unroll
          for (int r=0; r<16; ++r){
            const int kvg = kv0 + kb*32 + 4*hi + (r&3) + 8*(r>>2);
            if (kvg > qg) sacc[kb][r] = -1e30f;
          }
      }

      // --- online softmax: all 32 vals belong to row q = lane&31 ---
      float mx = sacc[0][0];
      #pragma unroll
      for (int r=1; r<16; ++r) mx = fmaxf(mx, sacc[0][r]);
      #pragma unroll
      for (int r=0; r<16; ++r) mx = fmaxf(mx, sacc[1][r]);
      mx = fmaxf(mx, __shfl_xor(mx, 32));
      // defer-max (T13): only rescale when some row grew past 2^8 headroom
      if (!__all((mx - m_run)*L2E <= 8.0f)){
        const float mn = fmaxf(m_run, mx);
        const float alpha = exp2f((m_run - mn)*L2E);
        m_run = mn;
        l_run *= alpha;
        oacc[0] *= alpha;
        oacc[1] *= alpha;
      }
      const float nc = m_run * L2E;
      float ps = 0.f;
      #pragma unroll
      for (int kb=0; kb<2; ++kb)
        #pragma unroll
        for (int r=0; r<16; ++r){
          float v = exp2f(__builtin_fmaf(sacc[kb][r], L2E, -nc));
          sacc[kb][r] = v;
          ps += v;
        }
      ps += __shfl_xor(ps, 32);
      l_run += ps;

      // --- P -> bf16 B-frags: cvt_pk pairs + permlane32_swap (T12) ---
      bf16x8 pa[4];
      #pragma unroll
      for (int kb=0; kb<2; ++kb){
        unsigned w[8];
        #pragma unroll
        for (int i=0; i<8; ++i){
          float a = sacc[kb][2*i], b2 = sacc[kb][2*i+1];
          asm("v_cvt_pk_bf16_f32 %0, %1, %2" : "=v"(w[i]) : "v"(a), "v"(b2));
        }
        auto s02 = __builtin_amdgcn_permlane32_swap(w[0], w[2], false, false);
        auto s13 = __builtin_amdgcn_permlane32_swap(w[1], w[3], false, false);
        auto s46 = __builtin_amdgcn_permlane32_swap(w[4], w[6], false, false);
        auto s57 = __builtin_amdgcn_permlane32_swap(w[5], w[7], false, false);
        u32x4 ua = {s02[0], s13[0], s02[1], s13[1]};
        u32x4 ub = {s46[0], s57[0], s46[1], s57[1]};
        pa[kb*2+0] = __builtin_bit_cast(bf16x8, ua);
        pa[kb*2+1] = __builtin_bit_cast(bf16x8, ub);
      }

      // --- O^T[dk][q] += V^T · P ---
      __builtin_amdgcn_s_setprio(1);
      #pragma unroll
      for (int dkb=0; dkb<2; ++dkb){
        const int vrow = dkb*32 + l31;
        #pragma unroll
        for (int ks=0; ks<4; ++ks){
          bf16x8 vf = *(const bf16x8*)&lV[cur][vrow*64 + (((ks*2+hi) ^ (vrow&7))<<3)];
          oacc[dkb] = MFMA32(vf, pa[ks], oacc[dkb]);
        }
      }
      __builtin_amdgcn_s_setprio(0);
    }
    __syncthreads();   // drains this wave's prefetch loads; all buffers ready
    cur ^= 1;
  }

  // --- epilogue: lane owns output row q=qg; dk = dkb*32 + 8*(r>>2) + 4*hi + (r&3)
  const float inv = 1.0f / l_run;
  #pragma unroll
  for (int dkb=0; dkb<2; ++dkb)
    #pragma unroll
    for (int rq=0; rq<4; ++rq){
      ushort4 w4;
      w4.x = f2bf(oacc[dkb][rq*4+0]*inv);
      w4.y = f2bf(oacc[dkb][rq*4+1]*inv);
      w4.z = f2bf(oacc[dkb][rq*4+2]*inv);
      w4.w = f2bf(oacc[dkb][rq*4+3]*inv);
      const int dk0 = dkb*32 + 8*rq + 4*hi;
      *(ushort4*)(O + (size_t)(b*S_+qg)*D_ + h*DK_ + dk0) = w4;
    }
}

// ---------------- launch ----------------
extern "C" void kernel_launch(void* const* d_in, const int* in_sizes, int n_in,
                              void* d_out, int out_size, void* d_ws, size_t ws_size,
                              hipStream_t stream){
  const float* x  = (const float*)d_in[0];
  const float* Wq = (const float*)d_in[1];
  const float* Wk = (const float*)d_in[2];
  const float* Wv = (const float*)d_in[3];
  const float* Wo = (const float*)d_in[4];
  float* out = (float*)d_out;
  char* ws = (char*)d_ws;

  size_t off = 0;
  u16* xb  = (u16*)(ws + off); off += (size_t)B_*S_*D_*2;
  u16* wqb = (u16*)(ws + off); off += (size_t)D_*D_*2;
  u16* wkb = (u16*)(ws + off); off += (size_t)D_*D_*2;
  u16* wvb = (u16*)(ws + off); off += (size_t)D_*D_*2;
  u16* wob = (u16*)(ws + off); off += (size_t)D_*D_*2;
  u16* Qb  = (u16*)(ws + off); off += (size_t)BH_*S_*DK_*2;
  u16* Kb  = (u16*)(ws + off); off += (size_t)BH_*S_*DK_*2;
  u16* Vtb = (u16*)(ws + off); off += (size_t)BH_*S_*DK_*2;   // [bh][dk][s]
  u16* Ob  = (u16*)(ws + off); off += (size_t)B_*S_*D_*2;
  float* ct = (float*)(ws + off); off += (size_t)S_*32*4;
  float* st = (float*)(ws + off); off += (size_t)S_*32*4;

  // merged preprocessing: x-cast + 4 weight casts + trig table in one launch
  prep_kernel<<<3328,256,0,stream>>>((const float4*)x,
                                     (const float4*)Wq, (const float4*)Wk,
                                     (const float4*)Wv, (const float4*)Wo,
                                     (ushort4*)xb, (ushort4*)wqb, ct, st);

  // QKV projections: flat grid 1536 = 3z x 64m x 8n, XCD-swizzled in-kernel;
  // z=0/1 epilogue applies RoPE in-place, Q pre-scaled by 1/sqrt(DK)=0.125
  gemm_bt<0><<<1536,256,0,stream>>>(xb, wqb,wkb,wvb, Qb,Kb,Vtb, nullptr, ct, st, D_);

  // causal flash attention (r2 structure; per-CU balanced qt permutation)
  attn_kernel<<<dim3(BH_, S_/128),256,0,stream>>>(Qb, Kb, Vtb, Ob);

  // output projection (fp32 out), flat grid 512
  gemm_bt<1><<<512,256,0,stream>>>(Ob, wob,wob,wob, nullptr,nullptr,nullptr, out, nullptr, nullptr, D_);
}